// Round 6
// baseline (1255.579 us; speedup 1.0000x reference)
//
#include <hip/hip_runtime.h>
#include <stdint.h>

#define TFAC 0.05f
#define BM 256
#define BN 256
#define BK 128
#define XCLIP 6.0f
#define SX (XCLIP / 127.0f)

typedef __attribute__((ext_vector_type(4))) int i32x4;

#define AS1(p) ((const __attribute__((address_space(1))) void*)(p))
#define AS3(p) ((__attribute__((address_space(3))) void*)(p))
#define SB0() __builtin_amdgcn_sched_barrier(0)

static __device__ __forceinline__ unsigned pack4(int b0, int b1, int b2, int b3) {
  return (unsigned)(unsigned char)b0 | ((unsigned)(unsigned char)b1 << 8) |
         ((unsigned)(unsigned char)b2 << 16) | ((unsigned)(unsigned char)b3 << 24);
}

// ---------------- weight quantization -> int8 ternary + f32 scale ----------------
__global__ __launch_bounds__(256) void quant_kernel(
    const float* __restrict__ W, unsigned* __restrict__ T,
    float* __restrict__ scale, int IN) {
  const int row = blockIdx.x;
  const int t = threadIdx.x;
  const float4* wr = reinterpret_cast<const float4*>(W + (size_t)row * IN);

  float4 v[4];
  float s = 0.f;
#pragma unroll
  for (int i = 0; i < 4; ++i) {
    v[i] = wr[i * 256 + t];
    s += fabsf(v[i].x) + fabsf(v[i].y) + fabsf(v[i].z) + fabsf(v[i].w);
  }
#pragma unroll
  for (int off = 1; off < 64; off <<= 1) s += __shfl_xor(s, off);
  __shared__ float red[4];
  if ((t & 63) == 0) red[t >> 6] = s;
  __syncthreads();
  const float tot = red[0] + red[1] + red[2] + red[3];
  const float thr = TFAC * tot / (float)IN;

  float cnt = 0.f, ms = 0.f;
  unsigned* trow = T + (size_t)row * (IN / 4);
#pragma unroll
  for (int i = 0; i < 4; ++i) {
    float e[4] = {v[i].x, v[i].y, v[i].z, v[i].w};
    int o[4];
#pragma unroll
    for (int j = 0; j < 4; ++j) {
      const float a = fabsf(e[j]);
      const bool m = a > thr;
      cnt += m ? 1.f : 0.f;
      ms += m ? a : 0.f;
      o[j] = m ? (e[j] > 0.f ? 1 : -1) : 0;
    }
    trow[i * 256 + t] = pack4(o[0], o[1], o[2], o[3]);
  }
#pragma unroll
  for (int off = 1; off < 64; off <<= 1) {
    cnt += __shfl_xor(cnt, off);
    ms += __shfl_xor(ms, off);
  }
  __shared__ float rc[4], rm[4];
  if ((t & 63) == 0) { rc[t >> 6] = cnt; rm[t >> 6] = ms; }
  __syncthreads();
  if (t == 0) {
    const float c = rc[0] + rc[1] + rc[2] + rc[3];
    const float m = rm[0] + rm[1] + rm[2] + rm[3];
    scale[row] = m / fmaxf(c, 1.f);
  }
}

// ---------------- x f32 -> i8 (global scale) ----------------
__global__ __launch_bounds__(256) void cvt_kernel(
    const float* __restrict__ X, unsigned* __restrict__ X8, size_t n4) {
  const size_t base = ((size_t)blockIdx.x * 256) * 4;
  const int t = threadIdx.x;
  const float inv = 127.0f / XCLIP;
#pragma unroll
  for (int i = 0; i < 4; ++i) {
    const size_t idx = base + (size_t)i * 256 + t;
    if (idx >= n4) return;
    const float4 a = reinterpret_cast<const float4*>(X)[idx];
    int b[4];
    b[0] = (int)rintf(fminf(fmaxf(a.x * inv, -127.f), 127.f));
    b[1] = (int)rintf(fminf(fmaxf(a.y * inv, -127.f), 127.f));
    b[2] = (int)rintf(fminf(fmaxf(a.z * inv, -127.f), 127.f));
    b[3] = (int)rintf(fminf(fmaxf(a.w * inv, -127.f), 127.f));
    X8[idx] = pack4(b[0], b[1], b[2], b[3]);
  }
}

// ---------------- 256x256 i8 NT GEMM: A direct-to-reg, B via LDS ----------------
static __device__ __forceinline__ void stage_half(
    const signed char* __restrict__ src, signed char* dst,
    size_t grow0, int k0, int K, int w, int lane) {
#pragma unroll
  for (int q = 0; q < 2; ++q) {
    const int base = w * 128 + q * 64;
    const int ci = base + lane;
    const int row = ci >> 3;
    const int cnat = (ci & 7) ^ (row & 7);
    const signed char* sp =
        src + (grow0 + (size_t)row) * (size_t)K + (size_t)(k0 + cnat * 16);
    __builtin_amdgcn_global_load_lds(AS1(sp), AS3(dst + base * 16), 16, 0, 0);
  }
}

static __device__ __forceinline__ i32x4 lds_read(
    const signed char* slot, int hrow, int kc) {
  const int byteoff = hrow * 128 + ((kc ^ (hrow & 7)) << 4);
  return *reinterpret_cast<const i32x4*>(slot + byteoff);
}

// issue 8 global A-fragment loads for one 64-row band (half = 0 or 1)
#define LOAD_A(DST, HALF, KOFF)                                               \
  _Pragma("unroll") for (int fl = 0; fl < 4; ++fl)                            \
  _Pragma("unroll") for (int ks = 0; ks < 2; ++ks)                            \
      DST[fl][ks] = *reinterpret_cast<const i32x4*>(                          \
          aBase + (size_t)((HALF) * 128 + fl * 16) * (size_t)K +              \
          (size_t)(KOFF) + ks * 64);

#define CLUST(AM, AR, BR, BN_)                                                \
  __builtin_amdgcn_s_setprio(1);                                              \
  _Pragma("unroll") for (int ks = 0; ks < 2; ++ks)                            \
  _Pragma("unroll") for (int fl = 0; fl < 4; ++fl)                            \
  _Pragma("unroll") for (int gl = 0; gl < 2; ++gl)                            \
      acc[AM + fl][BN_ + gl] = __builtin_amdgcn_mfma_i32_16x16x64_i8(         \
          AR[fl][ks], BR[gl][ks], acc[AM + fl][BN_ + gl], 0, 0, 0);           \
  __builtin_amdgcn_s_setprio(0);                                              \
  SB0();

__global__ __launch_bounds__(512, 2) void gemm_kernel(
    const signed char* __restrict__ A,    // x i8 [M][K]
    const signed char* __restrict__ Bt,   // tern i8 [N][K]
    const float* __restrict__ scale,      // [N]
    const float* __restrict__ bias,       // [N]
    float* __restrict__ C,                // [M][N]
    int M, int N, int K) {
  __shared__ signed char sB[4][128 * 128];   // 64 KiB: B only

  const int tid = (int)threadIdx.x;
  const int lane = tid & 63;
  const int w = tid >> 6;
  const int wm = w >> 2;   // 0..1
  const int wn = w & 3;    // 0..3
  const int lr = lane & 15;
  const int lg = lane >> 4;

  const int nbn = N / BN;
  const int nwg = (M / BM) * nbn;
  const int cpx = nwg >> 3;
  const int bid = (int)blockIdx.x;
  const int swz = (bid & 7) * cpx + (bid >> 3);
  const int bm = swz / nbn;
  const int bn = swz % nbn;
  const size_t rowA0 = (size_t)bm * BM;
  const size_t rowB0 = (size_t)bn * BN;

  const int NKT = K / BK;

  // per-lane A base: row = rowA0 + wm*64 + lr, col-byte = lg*16
  const signed char* aBase = A + (rowA0 + (size_t)(wm * 64 + lr)) * (size_t)K + lg * 16;

  i32x4 acc[8][4] = {};
  i32x4 arLo[4][2], arHi[4][2];

  // ---- prologue: B-stage tile 0 (oldest), then A fragments for tile 0 ----
  stage_half(Bt, sB[0], rowB0,       0, K, w, lane);
  stage_half(Bt, sB[1], rowB0 + 128, 0, K, w, lane);
  SB0();
  LOAD_A(arLo, 0, 0)
  LOAD_A(arHi, 1, 0)
  SB0();
  asm volatile("s_waitcnt vmcnt(16)" ::: "memory");  // drain B-stage(0); A in flight
  __builtin_amdgcn_s_barrier();

#pragma unroll 2
  for (int kt = 0; kt < NKT; ++kt) {
    const int p = (kt & 1) * 2;
    const int q = p ^ 2;
    const int ktn = (kt + 1 < NKT) ? kt + 1 : kt;  // clamp keeps vmcnt counts exact

    // stage B for tile kt+1 into opposite-parity slots (readers drained at end of kt-1)
    stage_half(Bt, sB[q],     rowB0,       ktn * BK, K, w, lane);
    stage_half(Bt, sB[q + 1], rowB0 + 128, ktn * BK, K, w, lane);
    SB0();

    // B fragments for this tile from LDS (compiler inserts counted lgkmcnt)
    i32x4 br0[2][2], br1[2][2];
#pragma unroll
    for (int gl = 0; gl < 2; ++gl)
#pragma unroll
      for (int ks = 0; ks < 2; ++ks)
        br0[gl][ks] = lds_read(sB[p], wn * 32 + gl * 16 + lr, ks * 4 + lg);
#pragma unroll
    for (int gl = 0; gl < 2; ++gl)
#pragma unroll
      for (int ks = 0; ks < 2; ++ks)
        br1[gl][ks] = lds_read(sB[p + 1], wn * 32 + gl * 16 + lr, ks * 4 + lg);
    SB0();

    CLUST(0, arLo, br0, 0)      // P0   (compiler waits vmcnt for arLo, lgkm for br0)
    CLUST(0, arLo, br1, 2)      // P1   (arLo dead after this)
    LOAD_A(arLo, 0, ktn * BK)   // A-lo for kt+1, ~1.5 clusters of lead
    SB0();
    CLUST(4, arHi, br1, 2)      // P2
    CLUST(4, arHi, br0, 0)      // P3   (arHi dead after this)
    LOAD_A(arHi, 1, ktn * BK)   // A-hi for kt+1, ~1 tile of lead
    SB0();

    // outstanding: Bstage(kt+1)=4 (oldest), arLo=8, arHi=8  -> drain the B stages
    asm volatile("s_waitcnt vmcnt(16)" ::: "memory");
    __builtin_amdgcn_s_barrier();
  }

  // ---- epilogue: y = acc * (SX*scale[col]) + bias[col] ----
#pragma unroll
  for (int g = 0; g < 4; ++g) {
    const int col = (int)rowB0 + (g >> 1) * 128 + wn * 32 + (g & 1) * 16 + lr;
    const float sc = SX * scale[col];
    const float bs = bias[col];
#pragma unroll
    for (int f = 0; f < 8; ++f) {
      const size_t r0 = rowA0 + (size_t)((f >> 2) * 128 + wm * 64 + (f & 3) * 16 + lg * 4);
#pragma unroll
      for (int r = 0; r < 4; ++r) {
        __builtin_nontemporal_store((float)acc[f][g][r] * sc + bs,
                                    &C[(r0 + r) * (size_t)N + col]);
      }
    }
  }
}

extern "C" void kernel_launch(void* const* d_in, const int* in_sizes, int n_in,
                              void* d_out, int out_size, void* d_ws, size_t ws_size,
                              hipStream_t stream) {
  (void)n_in; (void)out_size; (void)ws_size;
  const float* x = (const float*)d_in[0];
  const float* wgt = (const float*)d_in[1];
  const float* bias = (const float*)d_in[2];
  float* y = (float*)d_out;

  const int OUT = in_sizes[2];
  const int IN = in_sizes[1] / OUT;
  const int B = in_sizes[0] / IN;

  signed char* tern = (signed char*)d_ws;
  signed char* xb = (signed char*)((char*)d_ws + (size_t)OUT * IN);
  float* scale = (float*)((char*)d_ws + (size_t)OUT * IN + (size_t)B * IN);

  quant_kernel<<<OUT, 256, 0, stream>>>(wgt, (unsigned*)tern, scale, IN);

  const size_t n4 = (size_t)B * IN / 4;
  cvt_kernel<<<(unsigned)((n4 + 1023) / 1024), 256, 0, stream>>>(x, (unsigned*)xb, n4);

  gemm_kernel<<<(B / BM) * (OUT / BN), 512, 0, stream>>>(xb, tern, scale, bias, y, B, OUT, IN);
}

// Round 7
// 664.749 us; speedup vs baseline: 1.8888x; 1.8888x over previous
//
#include <hip/hip_runtime.h>
#include <stdint.h>

#define TFAC 0.05f
#define BM 256
#define BN 256
#define BK 128
#define XCLIP 6.0f
#define SX (XCLIP / 127.0f)

typedef __attribute__((ext_vector_type(4))) int i32x4;

#define AS1(p) ((const __attribute__((address_space(1))) void*)(p))
#define AS3(p) ((__attribute__((address_space(3))) void*)(p))
#define SB0() __builtin_amdgcn_sched_barrier(0)

static __device__ __forceinline__ unsigned pack4(int b0, int b1, int b2, int b3) {
  return (unsigned)(unsigned char)b0 | ((unsigned)(unsigned char)b1 << 8) |
         ((unsigned)(unsigned char)b2 << 16) | ((unsigned)(unsigned char)b3 << 24);
}

// ---------------- weight quantization -> int8 ternary + f32 scale ----------------
__global__ __launch_bounds__(256) void quant_kernel(
    const float* __restrict__ W, unsigned* __restrict__ T,
    float* __restrict__ scale, int IN) {
  const int row = blockIdx.x;
  const int t = threadIdx.x;
  const float4* wr = reinterpret_cast<const float4*>(W + (size_t)row * IN);

  float4 v[4];
  float s = 0.f;
#pragma unroll
  for (int i = 0; i < 4; ++i) {
    v[i] = wr[i * 256 + t];
    s += fabsf(v[i].x) + fabsf(v[i].y) + fabsf(v[i].z) + fabsf(v[i].w);
  }
#pragma unroll
  for (int off = 1; off < 64; off <<= 1) s += __shfl_xor(s, off);
  __shared__ float red[4];
  if ((t & 63) == 0) red[t >> 6] = s;
  __syncthreads();
  const float tot = red[0] + red[1] + red[2] + red[3];
  const float thr = TFAC * tot / (float)IN;

  float cnt = 0.f, ms = 0.f;
  unsigned* trow = T + (size_t)row * (IN / 4);
#pragma unroll
  for (int i = 0; i < 4; ++i) {
    float e[4] = {v[i].x, v[i].y, v[i].z, v[i].w};
    int o[4];
#pragma unroll
    for (int j = 0; j < 4; ++j) {
      const float a = fabsf(e[j]);
      const bool m = a > thr;
      cnt += m ? 1.f : 0.f;
      ms += m ? a : 0.f;
      o[j] = m ? (e[j] > 0.f ? 1 : -1) : 0;
    }
    trow[i * 256 + t] = pack4(o[0], o[1], o[2], o[3]);
  }
#pragma unroll
  for (int off = 1; off < 64; off <<= 1) {
    cnt += __shfl_xor(cnt, off);
    ms += __shfl_xor(ms, off);
  }
  __shared__ float rc[4], rm[4];
  if ((t & 63) == 0) { rc[t >> 6] = cnt; rm[t >> 6] = ms; }
  __syncthreads();
  if (t == 0) {
    const float c = rc[0] + rc[1] + rc[2] + rc[3];
    const float m = rm[0] + rm[1] + rm[2] + rm[3];
    scale[row] = m / fmaxf(c, 1.f);
  }
}

// ---------------- x f32 -> i8 (global scale) ----------------
__global__ __launch_bounds__(256) void cvt_kernel(
    const float* __restrict__ X, unsigned* __restrict__ X8, size_t n4) {
  const size_t base = ((size_t)blockIdx.x * 256) * 4;
  const int t = threadIdx.x;
  const float inv = 127.0f / XCLIP;
#pragma unroll
  for (int i = 0; i < 4; ++i) {
    const size_t idx = base + (size_t)i * 256 + t;
    if (idx >= n4) return;
    const float4 a = reinterpret_cast<const float4*>(X)[idx];
    int b[4];
    b[0] = (int)rintf(fminf(fmaxf(a.x * inv, -127.f), 127.f));
    b[1] = (int)rintf(fminf(fmaxf(a.y * inv, -127.f), 127.f));
    b[2] = (int)rintf(fminf(fmaxf(a.z * inv, -127.f), 127.f));
    b[3] = (int)rintf(fminf(fmaxf(a.w * inv, -127.f), 127.f));
    X8[idx] = pack4(b[0], b[1], b[2], b[3]);
  }
}

// ------- 256x256 i8 NT GEMM, BK=128, one-phase-lead fragment pipeline -------
static __device__ __forceinline__ i32x4 lds_read(
    const signed char* slot, int hrow, int kc) {
  const int byteoff = hrow * 128 + ((kc ^ (hrow & 7)) << 4);
  return *reinterpret_cast<const i32x4*>(slot + byteoff);
}

#define RD_A(DST, SLOT)                                                        \
  _Pragma("unroll") for (int fl = 0; fl < 4; ++fl)                             \
  _Pragma("unroll") for (int ks = 0; ks < 2; ++ks)                             \
      DST[fl][ks] = lds_read(SLOT, wm * 64 + fl * 16 + lr, ks * 4 + lg);

#define RD_B(DST, SLOT)                                                        \
  _Pragma("unroll") for (int gl = 0; gl < 2; ++gl)                             \
  _Pragma("unroll") for (int ks = 0; ks < 2; ++ks)                             \
      DST[gl][ks] = lds_read(SLOT, wn * 32 + gl * 16 + lr, ks * 4 + lg);

#define CLUST(AM, AR, BR, BN_)                                                 \
  __builtin_amdgcn_s_setprio(1);                                               \
  _Pragma("unroll") for (int ks = 0; ks < 2; ++ks)                             \
  _Pragma("unroll") for (int fl = 0; fl < 4; ++fl)                             \
  _Pragma("unroll") for (int gl = 0; gl < 2; ++gl)                             \
      acc[AM + fl][BN_ + gl] = __builtin_amdgcn_mfma_i32_16x16x64_i8(          \
          AR[fl][ks], BR[gl][ks], acc[AM + fl][BN_ + gl], 0, 0, 0);            \
  __builtin_amdgcn_s_setprio(0);                                               \
  SB0();

// stage one 128x128B half-tile (2 gload_lds per thread) from a precomputed
// per-thread base pointer; k0 selects the K-tile
#define STAGE(P0_, SLOT, K0)                                                   \
  __builtin_amdgcn_global_load_lds(AS1((P0_) + (K0)), AS3((SLOT) + dst0), 16, 0, 0); \
  __builtin_amdgcn_global_load_lds(AS1((P0_) + 8 * (size_t)K + (K0)), AS3((SLOT) + dst1), 16, 0, 0);

__global__ __launch_bounds__(512, 2) void gemm_kernel(
    const signed char* __restrict__ A,    // x i8 [M][K]
    const signed char* __restrict__ Bt,   // tern i8 [N][K]
    const float* __restrict__ scale,      // [N]
    const float* __restrict__ bias,       // [N]
    float* __restrict__ C,                // [M][N]
    int M, int N, int K) {
  __shared__ signed char sA[4][128 * 128];
  __shared__ signed char sB[4][128 * 128];

  const int tid = (int)threadIdx.x;
  const int lane = tid & 63;
  const int w = tid >> 6;
  const int wm = w >> 2;   // 0..1
  const int wn = w & 3;    // 0..3
  const int lr = lane & 15;
  const int lg = lane >> 4;

  const int nbn = N / BN;
  const int nwg = (M / BM) * nbn;
  const int cpx = nwg >> 3;
  const int bid = (int)blockIdx.x;
  const int swz = (bid & 7) * cpx + (bid >> 3);
  const int bm = swz / nbn;
  const int bn = swz % nbn;
  const size_t rowA0 = (size_t)bm * BM;
  const size_t rowB0 = (size_t)bn * BN;

  const int NKT = K / BK;

  // per-thread stage addressing: chunk ci = w*128 + q*64 + lane, row = ci>>3,
  // swizzled source chunk cnat = (ci&7)^(row&7); q=1 is ptr + 8*K.
  const int ci0 = w * 128 + lane;
  const int row0 = ci0 >> 3;
  const int cn0 = (ci0 & 7) ^ (row0 & 7);
  const int dst0 = ci0 * 16;
  const int dst1 = (ci0 + 64) * 16;
  const signed char* eA = A  + (rowA0 + 128 + (size_t)row0) * (size_t)K + cn0 * 16;  // A-hi
  const signed char* lA = A  + (rowA0 +       (size_t)row0) * (size_t)K + cn0 * 16;  // A-lo
  const signed char* eB = Bt + (rowB0 + 128 + (size_t)row0) * (size_t)K + cn0 * 16;  // B-hi
  const signed char* lB = Bt + (rowB0 +       (size_t)row0) * (size_t)K + cn0 * 16;  // B-lo

  i32x4 acc[8][4] = {};
  i32x4 arLo[4][2], arHi[4][2], br0[2][2], br1[2][2];

  // ---- prologue: tile0 all 4 halves + late{Alo,B0}[1]; then preload frags ----
  STAGE(lA, sA[0], 0)        // A-lo[0]
  STAGE(eA, sA[1], 0)        // A-hi[0]
  STAGE(lB, sB[0], 0)        // B-lo[0]
  STAGE(eB, sB[1], 0)        // B-hi[0]
  STAGE(lA, sA[2], BK)       // A-lo[1]  (late slot, parity q of tile 0)
  STAGE(lB, sB[2], BK)       // B-lo[1]
  asm volatile("s_waitcnt vmcnt(4)" ::: "memory");  // tile0's 8 loads landed
  __builtin_amdgcn_s_barrier();
  RD_A(arLo, sA[0])
  RD_B(br0, sB[0])
  asm volatile("s_waitcnt lgkmcnt(0)" ::: "memory");
  __builtin_amdgcn_s_barrier();   // no wave may overwrite sA[0]/sB[0] (late[2]) early

#pragma unroll 2
  for (int kt = 0; kt < NKT; ++kt) {
    const int p = (kt & 1) * 2;
    const int q = p ^ 2;
    const int kE = (kt + 1 < NKT ? kt + 1 : NKT - 1) * BK;
    const int kL = (kt + 2 < NKT ? kt + 2 : NKT - 1) * BK;

    // all 4 stages at tile top (slot-overwrite safe: tile-end barrier followed
    // every wave's lgkmcnt(0) drain of last tile's reads)
    STAGE(eA, sA[q + 1], kE)   // A-hi[kt+1]
    STAGE(eB, sB[q + 1], kE)   // B-hi[kt+1]
    STAGE(lA, sA[p], kL)       // A-lo[kt+2]
    STAGE(lB, sB[p], kL)       // B-lo[kt+2]
    SB0();

    // lead reads: br1 + arHi for this tile (slots staged last tile, vmcnt'd)
    RD_B(br1, sB[p + 1])
    RD_A(arHi, sA[p + 1])
    SB0();

    CLUST(0, arLo, br0, 0)     // P0 (lo,b0) — br1/arHi drain underneath
    CLUST(0, arLo, br1, 2)     // P1 (lo,b1) — waits br1 (counted); arHi drains
    RD_A(arLo, sA[q])          // next tile A-lo (late-staged at kt-1, ready)
    SB0();
    CLUST(4, arHi, br0, 0)     // P2 (hi,b0) — waits arHi (counted); arLo' drains
    RD_B(br0, sB[q])           // next tile B-lo (late-staged at kt-1, ready)
    SB0();
    CLUST(4, arHi, br1, 2)     // P3 (hi,b1) — no new wait; br0' drains

    asm volatile("s_waitcnt lgkmcnt(0)" ::: "memory");  // arLo'/br0' drained
    asm volatile("s_waitcnt vmcnt(4)" ::: "memory");    // tile kt+1 fully landed
    __builtin_amdgcn_s_barrier();
  }

  asm volatile("s_waitcnt vmcnt(0)" ::: "memory");

  // ---- epilogue: y = acc * (SX*scale[col]) + bias[col] ----
#pragma unroll
  for (int g = 0; g < 4; ++g) {
    const int col = (int)rowB0 + (g >> 1) * 128 + wn * 32 + (g & 1) * 16 + lr;
    const float sc = SX * scale[col];
    const float bs = bias[col];
#pragma unroll
    for (int f = 0; f < 8; ++f) {
      const size_t r0 = rowA0 + (size_t)((f >> 2) * 128 + wm * 64 + (f & 3) * 16 + lg * 4);
#pragma unroll
      for (int r = 0; r < 4; ++r) {
        __builtin_nontemporal_store((float)acc[f][g][r] * sc + bs,
                                    &C[(r0 + r) * (size_t)N + col]);
      }
    }
  }
}

extern "C" void kernel_launch(void* const* d_in, const int* in_sizes, int n_in,
                              void* d_out, int out_size, void* d_ws, size_t ws_size,
                              hipStream_t stream) {
  (void)n_in; (void)out_size; (void)ws_size;
  const float* x = (const float*)d_in[0];
  const float* wgt = (const float*)d_in[1];
  const float* bias = (const float*)d_in[2];
  float* y = (float*)d_out;

  const int OUT = in_sizes[2];
  const int IN = in_sizes[1] / OUT;
  const int B = in_sizes[0] / IN;

  signed char* tern = (signed char*)d_ws;
  signed char* xb = (signed char*)((char*)d_ws + (size_t)OUT * IN);
  float* scale = (float*)((char*)d_ws + (size_t)OUT * IN + (size_t)B * IN);

  quant_kernel<<<OUT, 256, 0, stream>>>(wgt, (unsigned*)tern, scale, IN);

  const size_t n4 = (size_t)B * IN / 4;
  cvt_kernel<<<(unsigned)((n4 + 1023) / 1024), 256, 0, stream>>>(x, (unsigned*)xb, n4);

  gemm_kernel<<<(B / BM) * (OUT / BN), 512, 0, stream>>>(xb, tern, scale, bias, y, B, OUT, IN);
}